// Round 1
// baseline (146.143 us; speedup 1.0000x reference)
//
#include <hip/hip_runtime.h>
#include <stddef.h>

// Problem dims (fixed by reference)
#define B  64
#define LQ 64
#define O  8
#define LO 32
#define S  64
#define W  32
#define D  512

#define NEG_BIG (-9.0e15f)

// Output layout (flat float, concatenated in return order)
#define QUE_CSF_SZ  (B*O*W*D)   // 8388608
#define MASK_SZ     (B*O*W)     // 16384
#define OFF_QMASK   (QUE_CSF_SZ)
#define OFF_OPT     (QUE_CSF_SZ + MASK_SZ)
#define OFF_OMASK   (QUE_CSF_SZ + MASK_SZ + QUE_CSF_SZ)

// Workspace layout (floats then ints)
#define WS_QSUM 0                         // B*D floats
#define WS_OSUM (B*D)                     // B*O*D floats
#define WS_CSUM (B*D + B*O*D)             // B*S*D floats
#define WS_FLOATS (B*D + B*O*D + B*S*D)   // 2,392,064 floats

// ---------------------------------------------------------------------------
// K1: fused row-sum reductions.
//   csum[b,s,d] = sum_w csf[b,s,w,d]     (blocks [0, B*S))
//   qsum[b,d]   = sum_q que[b,q,d]       (blocks [B*S, B*S+B))
//   osum[b,o,d] = sum_l opt[b,o,l,d]     (blocks [B*S+B, B*S+B+B*O))
// 128 threads/block, each thread owns one float4 column (4 d's).
// ---------------------------------------------------------------------------
__global__ __launch_bounds__(128) void k_sums(
    const float* __restrict__ que, const float* __restrict__ opt,
    const float* __restrict__ csf, float* __restrict__ ws) {
  const int blk = blockIdx.x;
  const int t = threadIdx.x;  // 0..127

  const float4* src;
  float4* dst;
  int rows;
  if (blk < B * S) {
    src = (const float4*)(csf + (size_t)blk * W * D);
    dst = (float4*)(ws + WS_CSUM + (size_t)blk * D);
    rows = W;
  } else if (blk < B * S + B) {
    const int b = blk - B * S;
    src = (const float4*)(que + (size_t)b * LQ * D);
    dst = (float4*)(ws + WS_QSUM + (size_t)b * D);
    rows = LQ;
  } else {
    const int bo = blk - B * S - B;
    src = (const float4*)(opt + (size_t)bo * LO * D);
    dst = (float4*)(ws + WS_OSUM + (size_t)bo * D);
    rows = LO;
  }

  float4 acc = make_float4(0.f, 0.f, 0.f, 0.f);
  for (int r = 0; r < rows; ++r) {
    float4 v = src[(size_t)r * (D / 4) + t];
    acc.x += v.x; acc.y += v.y; acc.z += v.z; acc.w += v.w;
  }
  dst[t] = acc;
}

// ---------------------------------------------------------------------------
// K2: que->csf argmax. One block (64 threads) per batch item; thread s
// computes dot(qsum[b], csum[b,s]) / csf_len[b,s]; wave argmax (first-index
// tie-break like jnp.argmax).
// ---------------------------------------------------------------------------
__global__ __launch_bounds__(64) void k_q2c(
    const float* __restrict__ ws, const unsigned char* __restrict__ csf_mask,
    int* __restrict__ ixq) {
  const int b = blockIdx.x;
  const int s = threadIdx.x;  // 0..63 = sentence index

  __shared__ float qs[D];
  for (int i = s; i < D; i += 64) qs[i] = ws[WS_QSUM + (size_t)b * D + i];
  __syncthreads();

  const float* row = ws + WS_CSUM + ((size_t)b * S + s) * D;
  float dot = 0.f;
  #pragma unroll 8
  for (int d = 0; d < D; ++d) dot += qs[d] * row[d];

  int valid = 0;
  const unsigned char* m = csf_mask + ((size_t)b * S + s) * W;
  for (int w = 0; w < W; ++w) valid += (m[w] == 0) ? 1 : 0;
  const float len = (valid == 0) ? NEG_BIG : (float)valid;
  float score = dot / len;

  int idx = s;
  for (int off = 32; off; off >>= 1) {
    float ov = __shfl_xor(score, off);
    int oi = __shfl_xor(idx, off);
    if (ov > score || (ov == score && oi < idx)) { score = ov; idx = oi; }
  }
  if (s == 0) ixq[b] = idx;
}

// ---------------------------------------------------------------------------
// K3: opt->csf argmax. One block (64 threads) per (b,o); thread s computes
// dot(osum[b,o], csum[b,s]) / csf_len[b,s]; wave argmax.
// ---------------------------------------------------------------------------
__global__ __launch_bounds__(64) void k_o2c(
    const float* __restrict__ ws, const unsigned char* __restrict__ csf_mask,
    int* __restrict__ ixo) {
  const int bo = blockIdx.x;        // b*O + o
  const int b = bo / O;
  const int s = threadIdx.x;

  __shared__ float os_[D];
  for (int i = s; i < D; i += 64) os_[i] = ws[WS_OSUM + (size_t)bo * D + i];
  __syncthreads();

  const float* row = ws + WS_CSUM + ((size_t)b * S + s) * D;
  float dot = 0.f;
  #pragma unroll 8
  for (int d = 0; d < D; ++d) dot += os_[d] * row[d];

  int valid = 0;
  const unsigned char* m = csf_mask + ((size_t)b * S + s) * W;
  for (int w = 0; w < W; ++w) valid += (m[w] == 0) ? 1 : 0;
  const float len = (valid == 0) ? NEG_BIG : (float)valid;
  float score = dot / len;

  int idx = s;
  for (int off = 32; off; off >>= 1) {
    float ov = __shfl_xor(score, off);
    int oi = __shfl_xor(idx, off);
    if (ov > score || (ov == score && oi < idx)) { score = ov; idx = oi; }
  }
  if (s == 0) ixo[bo] = idx;
}

// ---------------------------------------------------------------------------
// K4: gather + write all four outputs. One block (128 threads) per (b,o,w)
// row; each thread owns one float4 of D. Computes abs-sum for the masks.
//   que_csf[b,o,w,:] = opt_sum[b,o] ? 0 : csf[b, ixq[b], w, :]
//   opt_csf[b,o,w,:] = opt_sum[b,o] ? 0 : csf[0, ixo[b,o], w, :]
// ---------------------------------------------------------------------------
__global__ __launch_bounds__(128) void k_gather(
    const float* __restrict__ csf, const unsigned char* __restrict__ opt_sum,
    const int* __restrict__ ixq, const int* __restrict__ ixo,
    float* __restrict__ out) {
  const int bow = blockIdx.x;       // b*O*W + o*W + w
  const int w = bow % W;
  const int bo = bow / W;
  const int b = bo / O;
  const int t = threadIdx.x;        // 0..127

  const bool zero = (opt_sum[bo] != 0);

  float4 vq = make_float4(0.f, 0.f, 0.f, 0.f);
  float4 vo = make_float4(0.f, 0.f, 0.f, 0.f);
  if (!zero) {
    const int iq = ixq[b];
    const int io = ixo[bo];
    vq = ((const float4*)(csf + (((size_t)b * S + iq) * W + w) * D))[t];
    vo = ((const float4*)(csf + (((size_t)io) * W + w) * D))[t];
  }
  ((float4*)(out + (size_t)bow * D))[t] = vq;
  ((float4*)(out + OFF_OPT + (size_t)bow * D))[t] = vo;

  float aq = fabsf(vq.x) + fabsf(vq.y) + fabsf(vq.z) + fabsf(vq.w);
  float ao = fabsf(vo.x) + fabsf(vo.y) + fabsf(vo.z) + fabsf(vo.w);
  for (int off = 32; off; off >>= 1) {
    aq += __shfl_xor(aq, off);
    ao += __shfl_xor(ao, off);
  }

  __shared__ float sq[2], so[2];
  const int wave = t >> 6;
  if ((t & 63) == 0) { sq[wave] = aq; so[wave] = ao; }
  __syncthreads();
  if (t == 0) {
    const float tq = sq[0] + sq[1];
    const float to = so[0] + so[1];
    out[OFF_QMASK + bow] = (tq == 0.f) ? 1.f : 0.f;
    out[OFF_OMASK + bow] = (to == 0.f) ? 1.f : 0.f;
  }
}

extern "C" void kernel_launch(void* const* d_in, const int* in_sizes, int n_in,
                              void* d_out, int out_size, void* d_ws, size_t ws_size,
                              hipStream_t stream) {
  const float* que = (const float*)d_in[0];
  const float* opt = (const float*)d_in[1];
  const float* csf = (const float*)d_in[2];
  const unsigned char* csf_mask = (const unsigned char*)d_in[3];
  const unsigned char* opt_sum = (const unsigned char*)d_in[4];
  float* out = (float*)d_out;
  float* ws = (float*)d_ws;

  int* ixq = (int*)(ws + WS_FLOATS);        // B ints
  int* ixo = ixq + B;                        // B*O ints

  // K1: all three row-sum families in one launch
  k_sums<<<B * S + B + B * O, 128, 0, stream>>>(que, opt, csf, ws);

  // K2/K3: argmax score kernels (tiny)
  k_q2c<<<B, 64, 0, stream>>>(ws, csf_mask, ixq);
  k_o2c<<<B * O, 64, 0, stream>>>(ws, csf_mask, ixo);

  // K4: gather + masks
  k_gather<<<B * O * W, 128, 0, stream>>>(csf, opt_sum, ixq, ixo, out);
}

// Round 2
// 128.450 us; speedup vs baseline: 1.1377x; 1.1377x over previous
//
#include <hip/hip_runtime.h>
#include <stddef.h>

// Problem dims (fixed by reference)
#define B  64
#define LQ 64
#define O  8
#define LO 32
#define S  64
#define W  32
#define D  512

#define NEG_BIG (-9.0e15f)

// Output layout (flat float, concatenated in return order)
#define QUE_CSF_SZ  (B*O*W*D)   // 8388608
#define MASK_SZ     (B*O*W)     // 16384
#define OFF_QMASK   (QUE_CSF_SZ)
#define OFF_OPT     (QUE_CSF_SZ + MASK_SZ)
#define OFF_OMASK   (QUE_CSF_SZ + MASK_SZ + QUE_CSF_SZ)

// Workspace layout (floats then ints)
#define WS_QSUM 0                         // B*D floats
#define WS_OSUM (B*D)                     // B*O*D floats
#define WS_CSUM (B*D + B*O*D)             // B*S*D floats
#define WS_FLOATS (B*D + B*O*D + B*S*D)

// ---------------------------------------------------------------------------
// K1: fused row-sum reductions (streaming, BW-bound — this is ~310MB of reads)
//   csum[b,s,d] = sum_w csf[b,s,w,d]     (blocks [0, B*S))
//   qsum[b,d]   = sum_q que[b,q,d]       (blocks [B*S, B*S+B))
//   osum[b,o,d] = sum_l opt[b,o,l,d]     (blocks [B*S+B, B*S+B+B*O))
// 128 threads/block, each thread owns one float4 column. Compile-time trip
// counts so the compiler can keep many loads in flight.
// ---------------------------------------------------------------------------
template <int ROWS>
__device__ inline void rowsum(const float4* __restrict__ src,
                              float4* __restrict__ dst, int t) {
  float4 acc = make_float4(0.f, 0.f, 0.f, 0.f);
  #pragma unroll 8
  for (int r = 0; r < ROWS; ++r) {
    float4 v = src[(size_t)r * (D / 4) + t];
    acc.x += v.x; acc.y += v.y; acc.z += v.z; acc.w += v.w;
  }
  dst[t] = acc;
}

__global__ __launch_bounds__(128) void k_sums(
    const float* __restrict__ que, const float* __restrict__ opt,
    const float* __restrict__ csf, float* __restrict__ ws) {
  const int blk = blockIdx.x;
  const int t = threadIdx.x;  // 0..127

  if (blk < B * S) {
    rowsum<W>((const float4*)(csf + (size_t)blk * W * D),
              (float4*)(ws + WS_CSUM + (size_t)blk * D), t);
  } else if (blk < B * S + B) {
    const int b = blk - B * S;
    rowsum<LQ>((const float4*)(que + (size_t)b * LQ * D),
               (float4*)(ws + WS_QSUM + (size_t)b * D), t);
  } else {
    const int bo = blk - B * S - B;
    rowsum<LO>((const float4*)(opt + (size_t)bo * LO * D),
               (float4*)(ws + WS_OSUM + (size_t)bo * D), t);
  }
}

// ---------------------------------------------------------------------------
// K2: fused score + argmax for BOTH q2c and o2c.
// One block (256 threads = 4 waves) per batch item b. Each csum[b,s] row is
// read ONCE, coalesced (2 float4 per lane), and dotted against all 9 query
// vectors (qsum[b] + osum[b,0..7]) held in per-lane registers. Wave
// shuffle-reduce per dot; scores land in LDS; argmax per query with
// first-index tie-break (matches jnp.argmax).
// ---------------------------------------------------------------------------
#define RED(v)                                   \
  do {                                           \
    v += __shfl_xor(v, 32);                      \
    v += __shfl_xor(v, 16);                      \
    v += __shfl_xor(v, 8);                       \
    v += __shfl_xor(v, 4);                       \
    v += __shfl_xor(v, 2);                       \
    v += __shfl_xor(v, 1);                       \
  } while (0)

__device__ inline float dot8(float4 a0, float4 a1, float4 b0, float4 b1) {
  return a0.x * b0.x + a0.y * b0.y + a0.z * b0.z + a0.w * b0.w +
         a1.x * b1.x + a1.y * b1.y + a1.z * b1.z + a1.w * b1.w;
}

__global__ __launch_bounds__(256) void k_scores(
    const float* __restrict__ ws, const unsigned char* __restrict__ csf_mask,
    int* __restrict__ ixq, int* __restrict__ ixo) {
  const int b = blockIdx.x;
  const int t = threadIdx.x;
  const int wv = t >> 6;      // 0..3
  const int lane = t & 63;

  __shared__ float sc[9 * S];

  // Per-lane fragments of the 9 query vectors (8 floats each).
  const float4* qp = (const float4*)(ws + WS_QSUM + (size_t)b * D) + lane * 2;
  const float4 q0 = qp[0], q1 = qp[1];
  float4 p0[O], p1[O];
  #pragma unroll
  for (int o = 0; o < O; ++o) {
    const float4* op =
        (const float4*)(ws + WS_OSUM + ((size_t)b * O + o) * D) + lane * 2;
    p0[o] = op[0];
    p1[o] = op[1];
  }

  // Each wave handles 16 sentences.
  for (int i = 0; i < 16; ++i) {
    const int s = wv * 16 + i;
    const float4* cp =
        (const float4*)(ws + WS_CSUM + ((size_t)b * S + s) * D) + lane * 2;
    const float4 c0 = cp[0], c1 = cp[1];

    // csf_len via ballot over first W lanes
    int pad = 0;
    if (lane < W) pad = (csf_mask[((size_t)b * S + s) * W + lane] != 0) ? 1 : 0;
    const unsigned long long bal = __ballot(pad);
    const int valid = W - (int)__popcll(bal);
    const float len = (valid == 0) ? NEG_BIG : (float)valid;

    float dq = dot8(q0, q1, c0, c1);
    RED(dq);
    if (lane == 0) sc[0 * S + s] = dq / len;
    #pragma unroll
    for (int o = 0; o < O; ++o) {
      float dv = dot8(p0[o], p1[o], c0, c1);
      RED(dv);
      if (lane == 0) sc[(1 + o) * S + s] = dv / len;
    }
  }
  __syncthreads();

  // Argmax per query (9 queries over 4 waves).
  for (int q = wv; q < 9; q += 4) {
    float v = sc[q * S + lane];
    int idx = lane;
    for (int off = 32; off; off >>= 1) {
      float ov = __shfl_xor(v, off);
      int oi = __shfl_xor(idx, off);
      if (ov > v || (ov == v && oi < idx)) { v = ov; idx = oi; }
    }
    if (lane == 0) {
      if (q == 0) ixq[b] = idx;
      else ixo[b * O + (q - 1)] = idx;
    }
  }
}

// ---------------------------------------------------------------------------
// K3: gather + write all four outputs. One block (128 threads) per (b,o,w)
// row; each thread owns one float4 of D. Computes abs-sum for the masks.
//   que_csf[b,o,w,:] = opt_sum[b,o] ? 0 : csf[b, ixq[b], w, :]
//   opt_csf[b,o,w,:] = opt_sum[b,o] ? 0 : csf[0, ixo[b,o], w, :]
// ---------------------------------------------------------------------------
__global__ __launch_bounds__(128) void k_gather(
    const float* __restrict__ csf, const unsigned char* __restrict__ opt_sum,
    const int* __restrict__ ixq, const int* __restrict__ ixo,
    float* __restrict__ out) {
  const int bow = blockIdx.x;       // b*O*W + o*W + w
  const int w = bow % W;
  const int bo = bow / W;
  const int b = bo / O;
  const int t = threadIdx.x;        // 0..127

  const bool zero = (opt_sum[bo] != 0);

  float4 vq = make_float4(0.f, 0.f, 0.f, 0.f);
  float4 vo = make_float4(0.f, 0.f, 0.f, 0.f);
  if (!zero) {
    const int iq = ixq[b];
    const int io = ixo[bo];
    vq = ((const float4*)(csf + (((size_t)b * S + iq) * W + w) * D))[t];
    vo = ((const float4*)(csf + (((size_t)io) * W + w) * D))[t];
  }
  ((float4*)(out + (size_t)bow * D))[t] = vq;
  ((float4*)(out + OFF_OPT + (size_t)bow * D))[t] = vo;

  float aq = fabsf(vq.x) + fabsf(vq.y) + fabsf(vq.z) + fabsf(vq.w);
  float ao = fabsf(vo.x) + fabsf(vo.y) + fabsf(vo.z) + fabsf(vo.w);
  for (int off = 32; off; off >>= 1) {
    aq += __shfl_xor(aq, off);
    ao += __shfl_xor(ao, off);
  }

  __shared__ float sq[2], so[2];
  const int wave = t >> 6;
  if ((t & 63) == 0) { sq[wave] = aq; so[wave] = ao; }
  __syncthreads();
  if (t == 0) {
    const float tq = sq[0] + sq[1];
    const float to = so[0] + so[1];
    out[OFF_QMASK + bow] = (tq == 0.f) ? 1.f : 0.f;
    out[OFF_OMASK + bow] = (to == 0.f) ? 1.f : 0.f;
  }
}

extern "C" void kernel_launch(void* const* d_in, const int* in_sizes, int n_in,
                              void* d_out, int out_size, void* d_ws, size_t ws_size,
                              hipStream_t stream) {
  const float* que = (const float*)d_in[0];
  const float* opt = (const float*)d_in[1];
  const float* csf = (const float*)d_in[2];
  const unsigned char* csf_mask = (const unsigned char*)d_in[3];
  const unsigned char* opt_sum = (const unsigned char*)d_in[4];
  float* out = (float*)d_out;
  float* ws = (float*)d_ws;

  int* ixq = (int*)(ws + WS_FLOATS);        // B ints
  int* ixo = ixq + B;                        // B*O ints

  // K1: all three row-sum families in one launch (~310MB streamed)
  k_sums<<<B * S + B + B * O, 128, 0, stream>>>(que, opt, csf, ws);

  // K2: fused scores + argmax (reads csum once, coalesced)
  k_scores<<<B, 256, 0, stream>>>(ws, csf_mask, ixq, ixo);

  // K3: gather + masks (~67MB written)
  k_gather<<<B * O * W, 128, 0, stream>>>(csf, opt_sum, ixq, ixo, out);
}

// Round 3
// 79.729 us; speedup vs baseline: 1.8330x; 1.6111x over previous
//
#include <hip/hip_runtime.h>
#include <stddef.h>

// Problem dims (fixed by reference)
#define B  64
#define LQ 64
#define O  8
#define LO 32
#define S  64
#define W  32
#define D  512

#define NEG_BIG (-9.0e15f)

// Output layout (flat float, concatenated in return order)
#define QUE_CSF_SZ  (B*O*W*D)
#define MASK_SZ     (B*O*W)
#define OFF_QMASK   (QUE_CSF_SZ)
#define OFF_OPT     (QUE_CSF_SZ + MASK_SZ)
#define OFF_OMASK   (QUE_CSF_SZ + MASK_SZ + QUE_CSF_SZ)

// Workspace layout (floats)
#define WS_QSUM 0                    // B*D
#define WS_OSUM (B*D)                // B*O*D
#define WS_SC   (B*D + B*O*D)        // 9*B*S scores, layout [(q*B+b)*S+s]

using f4 = __attribute__((ext_vector_type(4))) float;

__device__ inline float dot4(f4 a, f4 b) {
  return a.x * b.x + a.y * b.y + a.z * b.z + a.w * b.w;
}

#define RED(v)                \
  do {                        \
    v += __shfl_xor(v, 32);   \
    v += __shfl_xor(v, 16);   \
    v += __shfl_xor(v, 8);    \
    v += __shfl_xor(v, 4);    \
    v += __shfl_xor(v, 2);    \
    v += __shfl_xor(v, 1);    \
  } while (0)

// ---------------------------------------------------------------------------
// K1: qsum[b,d] = sum_q que[b,q,d];  osum[b,o,d] = sum_l opt[b,o,l,d]
// 256 threads/block: threads 0-127 sum the low half of rows, 128-255 the high
// half (col = t&127 owns one f4 column); halves combined through LDS.
// ---------------------------------------------------------------------------
template <int ROWS>
__device__ inline void rowsum2(const f4* __restrict__ src, f4* __restrict__ dst,
                               int t) {
  const int half = t >> 7;       // 0 or 1
  const int col = t & 127;       // f4 column
  const f4* p = src + (size_t)(half * (ROWS / 2)) * (D / 4) + col;
  f4 acc = {0.f, 0.f, 0.f, 0.f};
  #pragma unroll
  for (int r = 0; r < ROWS / 2; ++r)
    acc += __builtin_nontemporal_load(p + (size_t)r * (D / 4));
  __shared__ f4 tmp[128];
  if (half == 1) tmp[col] = acc;
  __syncthreads();
  if (half == 0) dst[col] = acc + tmp[col];
}

__global__ __launch_bounds__(256) void k_qosum(
    const float* __restrict__ que, const float* __restrict__ opt,
    float* __restrict__ ws) {
  const int blk = blockIdx.x;
  const int t = threadIdx.x;
  if (blk < B) {
    rowsum2<LQ>((const f4*)(que + (size_t)blk * LQ * D),
                (f4*)(ws + WS_QSUM + (size_t)blk * D), t);
  } else {
    const int bo = blk - B;
    rowsum2<LO>((const f4*)(opt + (size_t)bo * LO * D),
                (f4*)(ws + WS_OSUM + (size_t)bo * D), t);
  }
}

// ---------------------------------------------------------------------------
// K2: the big streaming pass. One block (128 threads) per (b,s): stream
// csf[b,s] (64KB) once with nontemporal loads, accumulate the per-thread
// csum fragment in registers, dot against qsum[b] + osum[b,0..7] (L2-hot),
// block-reduce the 9 dots, divide by csf_len, write 9 scores. csum never
// touches memory.
// ---------------------------------------------------------------------------
__global__ __launch_bounds__(128) void k_score(
    const float* __restrict__ csf, const unsigned char* __restrict__ csf_mask,
    float* __restrict__ ws) {
  const int bs = blockIdx.x;        // b*S + s
  const int b = bs >> 6;
  const int s = bs & 63;
  const int t = threadIdx.x;        // 0..127, owns f4 column t
  const int wv = t >> 6;
  const int lane = t & 63;

  const f4* src = (const f4*)(csf + (size_t)bs * W * D) + t;
  f4 acc = {0.f, 0.f, 0.f, 0.f};
  #pragma unroll 16
  for (int r = 0; r < W; ++r)
    acc += __builtin_nontemporal_load(src + (size_t)r * (D / 4));

  // 9 dot partials against the hot qsum/osum table
  float pq = dot4(acc, ((const f4*)(ws + WS_QSUM + (size_t)b * D))[t]);
  float po[O];
  #pragma unroll
  for (int o = 0; o < O; ++o)
    po[o] = dot4(acc, ((const f4*)(ws + WS_OSUM + ((size_t)b * O + o) * D))[t]);

  RED(pq);
  #pragma unroll
  for (int o = 0; o < O; ++o) RED(po[o]);

  __shared__ float part[2][9];
  if (lane == 0) {
    part[wv][0] = pq;
    #pragma unroll
    for (int o = 0; o < O; ++o) part[wv][1 + o] = po[o];
  }

  // csf_len via per-wave ballot over first W lanes (same result in each wave)
  int pad = 0;
  if (lane < W) pad = (csf_mask[(size_t)bs * W + lane] != 0) ? 1 : 0;
  const unsigned long long bal = __ballot(pad);
  const int valid = W - (int)__popcll(bal);
  const float len = (valid == 0) ? NEG_BIG : (float)valid;

  __syncthreads();
  if (t < 9)
    ws[WS_SC + ((size_t)t * B + b) * S + s] = (part[0][t] + part[1][t]) / len;
}

// ---------------------------------------------------------------------------
// K3: gather + inline argmax + masks. One block (128 threads) per (b,o,w).
// wave0 argmaxes the q-scores of b, wave1 the o-scores of (b,o) (first-index
// tie-break = jnp.argmax). Then each thread gathers one f4 column and the
// block writes both output rows (nontemporal) + abs-sum masks.
// ---------------------------------------------------------------------------
__global__ __launch_bounds__(128) void k_gather(
    const float* __restrict__ csf, const unsigned char* __restrict__ opt_sum,
    const float* __restrict__ ws, float* __restrict__ out) {
  const int bow = blockIdx.x;       // b*O*W + o*W + w
  const int w = bow & 31;
  const int bo = bow >> 5;
  const int b = bo >> 3;
  const int o = bo & 7;
  const int t = threadIdx.x;
  const int wv = t >> 6;
  const int lane = t & 63;

  // inline argmax over the 64 sentence scores
  __shared__ int sh_ix[2];
  {
    const int q = (wv == 0) ? 0 : (1 + o);
    float v = ws[WS_SC + ((size_t)q * B + b) * S + lane];
    int idx = lane;
    for (int off = 32; off; off >>= 1) {
      float ov = __shfl_xor(v, off);
      int oi = __shfl_xor(idx, off);
      if (ov > v || (ov == v && oi < idx)) { v = ov; idx = oi; }
    }
    if (lane == 0) sh_ix[wv] = idx;
  }
  __syncthreads();

  const bool zero = (opt_sum[bo] != 0);
  f4 vq = {0.f, 0.f, 0.f, 0.f};
  f4 vo = {0.f, 0.f, 0.f, 0.f};
  if (!zero) {
    const int iq = sh_ix[0];
    const int io = sh_ix[1];
    vq = ((const f4*)(csf + (((size_t)b * S + iq) * W + w) * D))[t];
    vo = ((const f4*)(csf + (((size_t)io) * W + w) * D))[t];
  }
  __builtin_nontemporal_store(vq, (f4*)(out + (size_t)bow * D) + t);
  __builtin_nontemporal_store(vo, (f4*)(out + OFF_OPT + (size_t)bow * D) + t);

  float aq = fabsf(vq.x) + fabsf(vq.y) + fabsf(vq.z) + fabsf(vq.w);
  float ao = fabsf(vo.x) + fabsf(vo.y) + fabsf(vo.z) + fabsf(vo.w);
  for (int off = 32; off; off >>= 1) {
    aq += __shfl_xor(aq, off);
    ao += __shfl_xor(ao, off);
  }

  __shared__ float sq[2], so[2];
  if (lane == 0) { sq[wv] = aq; so[wv] = ao; }
  __syncthreads();
  if (t == 0) {
    out[OFF_QMASK + bow] = ((sq[0] + sq[1]) == 0.f) ? 1.f : 0.f;
    out[OFF_OMASK + bow] = ((so[0] + so[1]) == 0.f) ? 1.f : 0.f;
  }
}

extern "C" void kernel_launch(void* const* d_in, const int* in_sizes, int n_in,
                              void* d_out, int out_size, void* d_ws, size_t ws_size,
                              hipStream_t stream) {
  const float* que = (const float*)d_in[0];
  const float* opt = (const float*)d_in[1];
  const float* csf = (const float*)d_in[2];
  const unsigned char* csf_mask = (const unsigned char*)d_in[3];
  const unsigned char* opt_sum = (const unsigned char*)d_in[4];
  float* out = (float*)d_out;
  float* ws = (float*)d_ws;

  // K1: que/opt row sums (~42MB streamed, small)
  k_qosum<<<B + B * O, 256, 0, stream>>>(que, opt, ws);

  // K2: csf stream + fused scores (~268MB streamed — the dominant pass)
  k_score<<<B * S, 128, 0, stream>>>(csf, csf_mask, ws);

  // K3: argmax (inline, L2-hot) + gather + masks (~67MB written)
  k_gather<<<B * O * W, 128, 0, stream>>>(csf, opt_sum, ws, out);
}

// Round 4
// 71.917 us; speedup vs baseline: 2.0321x; 1.1086x over previous
//
#include <hip/hip_runtime.h>
#include <stddef.h>

// Problem dims (fixed by reference)
#define B  64
#define LQ 64
#define O  8
#define LO 32
#define S  64
#define W  32
#define D  512

#define NEG_BIG (-9.0e15f)

// Output layout (flat float, concatenated in return order)
#define QUE_CSF_SZ  (B*O*W*D)
#define MASK_SZ     (B*O*W)
#define OFF_QMASK   (QUE_CSF_SZ)
#define OFF_OPT     (QUE_CSF_SZ + MASK_SZ)
#define OFF_OMASK   (QUE_CSF_SZ + MASK_SZ + QUE_CSF_SZ)

// Workspace layout (floats)
#define WS_QSUM 0                    // B*D
#define WS_OSUM (B*D)                // B*O*D
#define WS_SC   (B*D + B*O*D)        // 9*B*S scores, layout [(q*B+b)*S+s]

using f4 = __attribute__((ext_vector_type(4))) float;

__device__ inline float dot4(f4 a, f4 b) {
  return a.x * b.x + a.y * b.y + a.z * b.z + a.w * b.w;
}

#define RED(v)                \
  do {                        \
    v += __shfl_xor(v, 32);   \
    v += __shfl_xor(v, 16);   \
    v += __shfl_xor(v, 8);    \
    v += __shfl_xor(v, 4);    \
    v += __shfl_xor(v, 2);    \
    v += __shfl_xor(v, 1);    \
  } while (0)

// ---------------------------------------------------------------------------
// K1: qsum[b,d] = sum_q que[b,q,d];  osum[b,o,d] = sum_l opt[b,o,l,d]
// 512 threads/block, 4-way row split (quarter = t>>7 owns ROWS/4 rows of
// f4 column t&127); quarters combined through LDS. Plain loads.
// ---------------------------------------------------------------------------
template <int ROWS>
__device__ inline void rowsum4(const f4* __restrict__ src, f4* __restrict__ dst,
                               int t) {
  const int quarter = t >> 7;    // 0..3
  const int col = t & 127;       // f4 column
  const f4* p = src + (size_t)(quarter * (ROWS / 4)) * (D / 4) + col;
  f4 acc = {0.f, 0.f, 0.f, 0.f};
  #pragma unroll
  for (int r = 0; r < ROWS / 4; ++r)
    acc += p[(size_t)r * (D / 4)];
  __shared__ f4 tmp[3][128];
  if (quarter) tmp[quarter - 1][col] = acc;
  __syncthreads();
  if (quarter == 0) dst[col] = acc + tmp[0][col] + tmp[1][col] + tmp[2][col];
}

__global__ __launch_bounds__(512) void k_qosum(
    const float* __restrict__ que, const float* __restrict__ opt,
    float* __restrict__ ws) {
  const int blk = blockIdx.x;
  const int t = threadIdx.x;
  if (blk < B) {
    rowsum4<LQ>((const f4*)(que + (size_t)blk * LQ * D),
                (f4*)(ws + WS_QSUM + (size_t)blk * D), t);
  } else {
    const int bo = blk - B;
    rowsum4<LO>((const f4*)(opt + (size_t)bo * LO * D),
                (f4*)(ws + WS_OSUM + (size_t)bo * D), t);
  }
}

// ---------------------------------------------------------------------------
// K2: the big streaming pass. One block (128 threads) per (b,s): stream
// csf[b,s] (64KB) once with PLAIN loads (A/B vs nt: m13's 6.29TB/s ceiling
// was plain loads), accumulate per-thread csum fragment in registers, dot
// against qsum[b] + osum[b,0..7] (L2-hot), block-reduce the 9 dots, divide
// by csf_len, write 9 scores. csum never touches memory.
// ---------------------------------------------------------------------------
__global__ __launch_bounds__(128) void k_score(
    const float* __restrict__ csf, const unsigned char* __restrict__ csf_mask,
    float* __restrict__ ws) {
  const int bs = blockIdx.x;        // b*S + s
  const int b = bs >> 6;
  const int s = bs & 63;
  const int t = threadIdx.x;        // 0..127, owns f4 column t
  const int wv = t >> 6;
  const int lane = t & 63;

  const f4* src = (const f4*)(csf + (size_t)bs * W * D) + t;
  f4 acc = {0.f, 0.f, 0.f, 0.f};
  #pragma unroll 16
  for (int r = 0; r < W; ++r)
    acc += src[(size_t)r * (D / 4)];

  // 9 dot partials against the hot qsum/osum table
  float pq = dot4(acc, ((const f4*)(ws + WS_QSUM + (size_t)b * D))[t]);
  float po[O];
  #pragma unroll
  for (int o = 0; o < O; ++o)
    po[o] = dot4(acc, ((const f4*)(ws + WS_OSUM + ((size_t)b * O + o) * D))[t]);

  RED(pq);
  #pragma unroll
  for (int o = 0; o < O; ++o) RED(po[o]);

  __shared__ float part[2][9];
  if (lane == 0) {
    part[wv][0] = pq;
    #pragma unroll
    for (int o = 0; o < O; ++o) part[wv][1 + o] = po[o];
  }

  // csf_len via per-wave ballot over first W lanes (same result in each wave)
  int pad = 0;
  if (lane < W) pad = (csf_mask[(size_t)bs * W + lane] != 0) ? 1 : 0;
  const unsigned long long bal = __ballot(pad);
  const int valid = W - (int)__popcll(bal);
  const float len = (valid == 0) ? NEG_BIG : (float)valid;

  __syncthreads();
  if (t < 9)
    ws[WS_SC + ((size_t)t * B + b) * S + s] = (part[0][t] + part[1][t]) / len;
}

// ---------------------------------------------------------------------------
// K3: gather + inline argmax + masks. One block (128 threads) per (b,o,w).
// wave0 argmaxes the q-scores of b, wave1 the o-scores of (b,o) (first-index
// tie-break = jnp.argmax). Then each thread gathers one f4 column and the
// block writes both output rows (nt stores) + abs-sum masks.
// ---------------------------------------------------------------------------
__global__ __launch_bounds__(128) void k_gather(
    const float* __restrict__ csf, const unsigned char* __restrict__ opt_sum,
    const float* __restrict__ ws, float* __restrict__ out) {
  const int bow = blockIdx.x;       // b*O*W + o*W + w
  const int w = bow & 31;
  const int bo = bow >> 5;
  const int b = bo >> 3;
  const int o = bo & 7;
  const int t = threadIdx.x;
  const int wv = t >> 6;
  const int lane = t & 63;

  // inline argmax over the 64 sentence scores
  __shared__ int sh_ix[2];
  {
    const int q = (wv == 0) ? 0 : (1 + o);
    float v = ws[WS_SC + ((size_t)q * B + b) * S + lane];
    int idx = lane;
    for (int off = 32; off; off >>= 1) {
      float ov = __shfl_xor(v, off);
      int oi = __shfl_xor(idx, off);
      if (ov > v || (ov == v && oi < idx)) { v = ov; idx = oi; }
    }
    if (lane == 0) sh_ix[wv] = idx;
  }
  __syncthreads();

  const bool zero = (opt_sum[bo] != 0);
  f4 vq = {0.f, 0.f, 0.f, 0.f};
  f4 vo = {0.f, 0.f, 0.f, 0.f};
  if (!zero) {
    const int iq = sh_ix[0];
    const int io = sh_ix[1];
    vq = ((const f4*)(csf + (((size_t)b * S + iq) * W + w) * D))[t];
    vo = ((const f4*)(csf + (((size_t)io) * W + w) * D))[t];
  }
  __builtin_nontemporal_store(vq, (f4*)(out + (size_t)bow * D) + t);
  __builtin_nontemporal_store(vo, (f4*)(out + OFF_OPT + (size_t)bow * D) + t);

  float aq = fabsf(vq.x) + fabsf(vq.y) + fabsf(vq.z) + fabsf(vq.w);
  float ao = fabsf(vo.x) + fabsf(vo.y) + fabsf(vo.z) + fabsf(vo.w);
  for (int off = 32; off; off >>= 1) {
    aq += __shfl_xor(aq, off);
    ao += __shfl_xor(ao, off);
  }

  __shared__ float sq[2], so[2];
  if (lane == 0) { sq[wv] = aq; so[wv] = ao; }
  __syncthreads();
  if (t == 0) {
    out[OFF_QMASK + bow] = ((sq[0] + sq[1]) == 0.f) ? 1.f : 0.f;
    out[OFF_OMASK + bow] = ((so[0] + so[1]) == 0.f) ? 1.f : 0.f;
  }
}

extern "C" void kernel_launch(void* const* d_in, const int* in_sizes, int n_in,
                              void* d_out, int out_size, void* d_ws, size_t ws_size,
                              hipStream_t stream) {
  const float* que = (const float*)d_in[0];
  const float* opt = (const float*)d_in[1];
  const float* csf = (const float*)d_in[2];
  const unsigned char* csf_mask = (const unsigned char*)d_in[3];
  const unsigned char* opt_sum = (const unsigned char*)d_in[4];
  float* out = (float*)d_out;
  float* ws = (float*)d_ws;

  // K1: que/opt row sums (~42MB streamed, short critical head)
  k_qosum<<<B + B * O, 512, 0, stream>>>(que, opt, ws);

  // K2: csf stream + fused scores (~268MB streamed — the dominant pass)
  k_score<<<B * S, 128, 0, stream>>>(csf, csf_mask, ws);

  // K3: argmax (inline, L2-hot) + gather + masks (~67MB written)
  k_gather<<<B * O * W, 128, 0, stream>>>(csf, opt_sum, ws, out);
}

// Round 5
// 70.629 us; speedup vs baseline: 2.0692x; 1.0182x over previous
//
#include <hip/hip_runtime.h>
#include <hip/hip_cooperative_groups.h>
#include <stddef.h>

namespace cg = cooperative_groups;

// Problem dims (fixed by reference)
#define B  64
#define LQ 64
#define O  8
#define LO 32
#define S  64
#define W  32
#define D  512

#define NEG_BIG (-9.0e15f)

// Output layout (flat float, concatenated in return order)
#define QUE_CSF_SZ  (B*O*W*D)
#define MASK_SZ     (B*O*W)
#define OFF_QMASK   (QUE_CSF_SZ)
#define OFF_OPT     (QUE_CSF_SZ + MASK_SZ)
#define OFF_OMASK   (QUE_CSF_SZ + MASK_SZ + QUE_CSF_SZ)

// Workspace layout (floats)
#define WS_QSUMH 0                         // B*2*D   (qsum halves)
#define WS_OSUM  (B*2*D)                   // B*O*D
#define WS_SC    (B*2*D + B*O*D)           // 9*B*S scores [(q*B+b)*S+s]

// Fused-kernel geometry: 4736 groups of (32 rows x 512 cols) = 64KB each.
// 2368 blocks x 128 thr, exactly 2 groups per block (g = blk, blk+2368).
//   groups [0,4096)    : csf (b,s)  -> csum fragment kept in registers
//   groups [4096,4224) : que half   -> ws qsumH
//   groups [4224,4736) : opt (b,o)  -> ws osum
#define NBLK 2368

using f4 = __attribute__((ext_vector_type(4))) float;

__device__ inline float dot4(f4 a, f4 b) {
  return a.x * b.x + a.y * b.y + a.z * b.z + a.w * b.w;
}

#define RED(v)                \
  do {                        \
    v += __shfl_xor(v, 32);   \
    v += __shfl_xor(v, 16);   \
    v += __shfl_xor(v, 8);    \
    v += __shfl_xor(v, 4);    \
    v += __shfl_xor(v, 2);    \
    v += __shfl_xor(v, 1);    \
  } while (0)

// Sum 32 rows of one f4 column (col = t), row stride 128 f4 (= 512 floats).
__device__ inline f4 stream32(const f4* __restrict__ p, int t) {
  f4 acc = {0.f, 0.f, 0.f, 0.f};
  #pragma unroll 8
  for (int r = 0; r < 32; ++r) acc += p[(size_t)r * 128 + t];
  return acc;
}

// 9 dots of a csum fragment against qsum[b] (2 halves) + osum[b,0..7];
// per-wave reduce; lane0 deposits into part[wv][0..8].
__device__ inline void dots9(const float* __restrict__ ws, f4 acc, int b,
                             int wv, int lane, float part[2][9]) {
  const f4* qh = (const f4*)(ws + WS_QSUMH) + (size_t)b * 256;
  const int t = wv * 64 + lane;
  f4 qs = qh[t] + qh[128 + t];
  float pq = dot4(acc, qs);
  float po[O];
  #pragma unroll
  for (int o = 0; o < O; ++o)
    po[o] = dot4(acc, ((const f4*)(ws + WS_OSUM))[((size_t)(b * O + o)) * 128 + t]);
  RED(pq);
  #pragma unroll
  for (int o = 0; o < O; ++o) RED(po[o]);
  if (lane == 0) {
    part[wv][0] = pq;
    #pragma unroll
    for (int o = 0; o < O; ++o) part[wv][1 + o] = po[o];
  }
}

// ---------------------------------------------------------------------------
// Fused cooperative kernel: phase A streams ALL inputs (310MB, BW-bound, no
// serialization of que/opt sums behind csf); grid sync; phase B computes the
// 9 scores per csf group from the register-held csum fragments.
// ---------------------------------------------------------------------------
__global__ __launch_bounds__(128, 5) void k_fused(
    const float* __restrict__ que, const float* __restrict__ opt,
    const float* __restrict__ csf, const unsigned char* __restrict__ csf_mask,
    float* __restrict__ ws) {
  const int blk = blockIdx.x;
  const int t = threadIdx.x;      // 0..127, owns f4 column t
  const int wv = t >> 6;
  const int lane = t & 63;
  const int g1 = blk + NBLK;
  const bool j1csf = (g1 < 4096);

  // ---- phase A: stream 2 x 64KB groups ----
  f4 acc0 = stream32((const f4*)csf + (size_t)blk * 4096, t);
  f4 acc1;
  if (j1csf) {
    acc1 = stream32((const f4*)csf + (size_t)g1 * 4096, t);
  } else if (g1 < 4224) {
    const int idx = g1 - 4096;            // b*2 + half
    const int b = idx >> 1, h = idx & 1;
    acc1 = stream32((const f4*)que + ((size_t)b * LQ + h * 32) * 128, t);
    ((f4*)(ws + WS_QSUMH))[(size_t)idx * 128 + t] = acc1;
  } else {
    const int bo = g1 - 4224;
    acc1 = stream32((const f4*)opt + (size_t)bo * LO * 128, t);
    ((f4*)(ws + WS_OSUM))[(size_t)bo * 128 + t] = acc1;
  }

  __threadfence();
  cg::this_grid().sync();

  // ---- phase B: scores ----
  __shared__ float part[2][2][9];   // [j][wave][query]
  dots9(ws, acc0, blk >> 6, wv, lane, part[0]);
  if (j1csf) dots9(ws, acc1, g1 >> 6, wv, lane, part[1]);

  // csf_len: wave0 computes len for group blk, wave1 for group g1
  float len;
  {
    const int bs = (wv == 0) ? blk : g1;
    int pad = 0;
    if (lane < W && (wv == 0 || j1csf))
      pad = (csf_mask[(size_t)bs * W + lane] != 0) ? 1 : 0;
    const unsigned long long bal = __ballot(pad);
    const int valid = W - (int)__popcll(bal);
    len = (valid == 0) ? NEG_BIG : (float)valid;
  }
  __syncthreads();

  if (t < 9) {
    const int b0 = blk >> 6, s0 = blk & 63;
    ws[WS_SC + ((size_t)t * B + b0) * S + s0] =
        (part[0][0][t] + part[0][1][t]) / len;
  }
  if (j1csf && t >= 64 && t < 73) {
    const int q = t - 64;
    const int b1 = g1 >> 6, s1 = g1 & 63;
    ws[WS_SC + ((size_t)q * B + b1) * S + s1] =
        (part[1][0][q] + part[1][1][q]) / len;
  }
}

// ---------------------------------------------------------------------------
// Legacy fallback path (only if cooperative launch unavailable): K1 sums,
// then K2 scores. Same ws layout as k_fused.
// ---------------------------------------------------------------------------
template <int ROWS>
__device__ inline void rowsum4(const f4* __restrict__ src, f4* __restrict__ dst,
                               int t) {
  const int quarter = t >> 7;
  const int col = t & 127;
  const f4* p = src + (size_t)(quarter * (ROWS / 4)) * 128 + col;
  f4 acc = {0.f, 0.f, 0.f, 0.f};
  #pragma unroll
  for (int r = 0; r < ROWS / 4; ++r) acc += p[(size_t)r * 128];
  __shared__ f4 tmp[3][128];
  if (quarter) tmp[quarter - 1][col] = acc;
  __syncthreads();
  if (quarter == 0) dst[col] = acc + tmp[0][col] + tmp[1][col] + tmp[2][col];
}

__global__ __launch_bounds__(512) void k_qosum(
    const float* __restrict__ que, const float* __restrict__ opt,
    float* __restrict__ ws) {
  const int blk = blockIdx.x;
  const int t = threadIdx.x;
  if (blk < B) {
    rowsum4<LQ>((const f4*)que + (size_t)blk * LQ * 128,
                (f4*)(ws + WS_QSUMH) + (size_t)blk * 256, t);
    if (t < 128) {  // zero the unused second half slot
      f4 z = {0.f, 0.f, 0.f, 0.f};
      ((f4*)(ws + WS_QSUMH))[(size_t)blk * 256 + 128 + t] = z;
    }
  } else {
    const int bo = blk - B;
    rowsum4<LO>((const f4*)opt + (size_t)bo * LO * 128,
                (f4*)(ws + WS_OSUM) + (size_t)bo * 128, t);
  }
}

__global__ __launch_bounds__(128) void k_score(
    const float* __restrict__ csf, const unsigned char* __restrict__ csf_mask,
    float* __restrict__ ws) {
  const int bs = blockIdx.x;
  const int b = bs >> 6;
  const int s = bs & 63;
  const int t = threadIdx.x;
  const int wv = t >> 6;
  const int lane = t & 63;

  f4 acc = stream32((const f4*)csf + (size_t)bs * 4096, t);

  __shared__ float part[2][9];
  dots9(ws, acc, b, wv, lane, part);

  int pad = 0;
  if (lane < W) pad = (csf_mask[(size_t)bs * W + lane] != 0) ? 1 : 0;
  const unsigned long long bal = __ballot(pad);
  const int valid = W - (int)__popcll(bal);
  const float len = (valid == 0) ? NEG_BIG : (float)valid;

  __syncthreads();
  if (t < 9)
    ws[WS_SC + ((size_t)t * B + b) * S + s] = (part[0][t] + part[1][t]) / len;
}

// ---------------------------------------------------------------------------
// K3: gather + inline argmax + masks (unchanged from R4).
// ---------------------------------------------------------------------------
__global__ __launch_bounds__(128) void k_gather(
    const float* __restrict__ csf, const unsigned char* __restrict__ opt_sum,
    const float* __restrict__ ws, float* __restrict__ out) {
  const int bow = blockIdx.x;       // b*O*W + o*W + w
  const int w = bow & 31;
  const int bo = bow >> 5;
  const int b = bo >> 3;
  const int o = bo & 7;
  const int t = threadIdx.x;
  const int wv = t >> 6;
  const int lane = t & 63;

  __shared__ int sh_ix[2];
  {
    const int q = (wv == 0) ? 0 : (1 + o);
    float v = ws[WS_SC + ((size_t)q * B + b) * S + lane];
    int idx = lane;
    for (int off = 32; off; off >>= 1) {
      float ov = __shfl_xor(v, off);
      int oi = __shfl_xor(idx, off);
      if (ov > v || (ov == v && oi < idx)) { v = ov; idx = oi; }
    }
    if (lane == 0) sh_ix[wv] = idx;
  }
  __syncthreads();

  const bool zero = (opt_sum[bo] != 0);
  f4 vq = {0.f, 0.f, 0.f, 0.f};
  f4 vo = {0.f, 0.f, 0.f, 0.f};
  if (!zero) {
    const int iq = sh_ix[0];
    const int io = sh_ix[1];
    vq = ((const f4*)csf)[(((size_t)b * S + iq) * W + w) * 128 + t];
    vo = ((const f4*)csf)[((size_t)io * W + w) * 128 + t];
  }
  __builtin_nontemporal_store(vq, (f4*)(out + (size_t)bow * D) + t);
  __builtin_nontemporal_store(vo, (f4*)(out + OFF_OPT + (size_t)bow * D) + t);

  float aq = fabsf(vq.x) + fabsf(vq.y) + fabsf(vq.z) + fabsf(vq.w);
  float ao = fabsf(vo.x) + fabsf(vo.y) + fabsf(vo.z) + fabsf(vo.w);
  for (int off = 32; off; off >>= 1) {
    aq += __shfl_xor(aq, off);
    ao += __shfl_xor(ao, off);
  }

  __shared__ float sq[2], so[2];
  if (lane == 0) { sq[wv] = aq; so[wv] = ao; }
  __syncthreads();
  if (t == 0) {
    out[OFF_QMASK + bow] = ((sq[0] + sq[1]) == 0.f) ? 1.f : 0.f;
    out[OFF_OMASK + bow] = ((so[0] + so[1]) == 0.f) ? 1.f : 0.f;
  }
}

extern "C" void kernel_launch(void* const* d_in, const int* in_sizes, int n_in,
                              void* d_out, int out_size, void* d_ws, size_t ws_size,
                              hipStream_t stream) {
  const float* que = (const float*)d_in[0];
  const float* opt = (const float*)d_in[1];
  const float* csf = (const float*)d_in[2];
  const unsigned char* csf_mask = (const unsigned char*)d_in[3];
  const unsigned char* opt_sum = (const unsigned char*)d_in[4];
  float* out = (float*)d_out;
  float* ws = (float*)d_ws;

  // Cooperative path: requires all NBLK blocks co-resident.
  int coop = 0;
  {
    int dev = 0;
    hipDeviceProp_t prop{};
    int mb = 0;
    if (hipGetDevice(&dev) == hipSuccess &&
        hipGetDeviceProperties(&prop, dev) == hipSuccess &&
        hipOccupancyMaxActiveBlocksPerMultiprocessor(&mb, k_fused, 128, 0) ==
            hipSuccess) {
      if (prop.cooperativeLaunch &&
          (long)mb * prop.multiProcessorCount >= NBLK)
        coop = 1;
    }
  }

  if (coop) {
    void* args[] = {(void*)&que, (void*)&opt, (void*)&csf, (void*)&csf_mask,
                    (void*)&ws};
    if (hipLaunchCooperativeKernel(k_fused, dim3(NBLK), dim3(128), args, 0,
                                   stream) != hipSuccess)
      coop = 0;
  }
  if (!coop) {
    // Legacy path: sums then scores as separate launches.
    k_qosum<<<B + B * O, 512, 0, stream>>>(que, opt, ws);
    k_score<<<B * S, 128, 0, stream>>>(csf, csf_mask, ws);
  }

  // K3: argmax (inline, L2-hot) + gather + masks (~67MB written)
  k_gather<<<B * O * W, 128, 0, stream>>>(csf, opt_sum, ws, out);
}

// Round 6
// 70.585 us; speedup vs baseline: 2.0705x; 1.0006x over previous
//
#include <hip/hip_runtime.h>
#include <hip/hip_cooperative_groups.h>
#include <stddef.h>

namespace cg = cooperative_groups;

// Problem dims (fixed by reference)
#define B  64
#define LQ 64
#define O  8
#define LO 32
#define S  64
#define W  32
#define D  512

#define NEG_BIG (-9.0e15f)

// Output layout (flat float, concatenated in return order)
#define QUE_CSF_SZ  (B*O*W*D)
#define MASK_SZ     (B*O*W)
#define OFF_QMASK   (QUE_CSF_SZ)
#define OFF_OPT     (QUE_CSF_SZ + MASK_SZ)
#define OFF_OMASK   (QUE_CSF_SZ + MASK_SZ + QUE_CSF_SZ)

// Workspace layout (floats)
#define WS_QSUMH 0                         // B*2*D   (qsum halves)
#define WS_OSUM  (B*2*D)                   // B*O*D
#define WS_SC    (B*2*D + B*O*D)           // 9*B*S scores [(q*B+b)*S+s]

// Geometry: 4736 chunks of 64KB (16384 floats = 4096 f4).
//   chunks [0,4096)    : csf (b,s)  -> csum fragment kept in registers
//   chunks [4096,4224) : que half   -> ws qsumH
//   chunks [4224,4736) : opt (b,o)  -> ws osum
// 2368 blocks x 128 thr; block blk streams chunks {blk, blk+2368} interleaved.
#define NBLK 2368

using f4 = __attribute__((ext_vector_type(4))) float;

__device__ inline float dot4(f4 a, f4 b) {
  return a.x * b.x + a.y * b.y + a.z * b.z + a.w * b.w;
}

#define RED(v)                \
  do {                        \
    v += __shfl_xor(v, 32);   \
    v += __shfl_xor(v, 16);   \
    v += __shfl_xor(v, 8);    \
    v += __shfl_xor(v, 4);    \
    v += __shfl_xor(v, 2);    \
    v += __shfl_xor(v, 1);    \
  } while (0)

// argmax over 64 lane-values with first-index tie-break (jnp.argmax);
// butterfly leaves the winning index in EVERY lane.
#define ARGMAX(v, idx)                                         \
  do {                                                         \
    for (int off_ = 32; off_; off_ >>= 1) {                    \
      float ov_ = __shfl_xor(v, off_);                         \
      int oi_ = __shfl_xor(idx, off_);                         \
      if (ov_ > v || (ov_ == v && oi_ < idx)) { v = ov_; idx = oi_; } \
    }                                                          \
  } while (0)

// 9 dots of a csum fragment against qsum[b] (2 halves) + osum[b,0..7];
// per-wave reduce; lane0 deposits into part[wv][0..8].
__device__ inline void dots9(const float* __restrict__ ws, f4 acc, int b,
                             int wv, int lane, float part[2][9]) {
  const f4* qh = (const f4*)(ws + WS_QSUMH) + (size_t)b * 256;
  const int t = wv * 64 + lane;
  f4 qs = qh[t] + qh[128 + t];
  float pq = dot4(acc, qs);
  float po[O];
  #pragma unroll
  for (int o = 0; o < O; ++o)
    po[o] = dot4(acc, ((const f4*)(ws + WS_OSUM))[((size_t)(b * O + o)) * 128 + t]);
  RED(pq);
  #pragma unroll
  for (int o = 0; o < O; ++o) RED(po[o]);
  if (lane == 0) {
    part[wv][0] = pq;
    #pragma unroll
    for (int o = 0; o < O; ++o) part[wv][1 + o] = po[o];
  }
}

// ---------------------------------------------------------------------------
// One cooperative kernel, three phases:
//   A: stream ALL inputs (310MB) — two interleaved 64KB chunks per block
//   sync
//   B: 9 scores per csf chunk from register-held csum fragments
//   sync
//   C: per-wave gather + argmax + output writes (67MB, nt stores)
// ---------------------------------------------------------------------------
__global__ __launch_bounds__(128, 5) void k_fused(
    const float* __restrict__ que, const float* __restrict__ opt,
    const float* __restrict__ csf, const unsigned char* __restrict__ csf_mask,
    const unsigned char* __restrict__ opt_sum, float* __restrict__ ws,
    float* __restrict__ out) {
  const int blk = blockIdx.x;
  const int t = threadIdx.x;      // 0..127, owns f4 column t
  const int wv = t >> 6;
  const int lane = t & 63;
  const int g1 = blk + NBLK;
  const bool j1csf = (g1 < 4096);

  // ---- phase A: two interleaved 64KB streams ----
  const f4* p0 = (const f4*)csf + (size_t)blk * 4096 + t;
  const f4* p1;
  if (j1csf)            p1 = (const f4*)csf + (size_t)g1 * 4096 + t;
  else if (g1 < 4224)   p1 = (const f4*)que + (size_t)(g1 - 4096) * 4096 + t;
  else                  p1 = (const f4*)opt + (size_t)(g1 - 4224) * 4096 + t;

  f4 acc0 = {0.f, 0.f, 0.f, 0.f};
  f4 acc1 = {0.f, 0.f, 0.f, 0.f};
  #pragma unroll 8
  for (int r = 0; r < 32; ++r) {
    acc0 += p0[(size_t)r * 128];
    acc1 += p1[(size_t)r * 128];
  }
  if (!j1csf) {
    if (g1 < 4224)
      ((f4*)(ws + WS_QSUMH))[(size_t)(g1 - 4096) * 128 + t] = acc1;
    else
      ((f4*)(ws + WS_OSUM))[(size_t)(g1 - 4224) * 128 + t] = acc1;
  }

  __threadfence();
  cg::this_grid().sync();

  // ---- phase B: scores ----
  __shared__ float part[2][2][9];   // [chunk][wave][query]
  dots9(ws, acc0, blk >> 6, wv, lane, part[0]);
  if (j1csf) dots9(ws, acc1, g1 >> 6, wv, lane, part[1]);

  float len;  // wave0: len(blk); wave1: len(g1)
  {
    const int bs = (wv == 0) ? blk : g1;
    int pad = 0;
    if (lane < W && (wv == 0 || j1csf))
      pad = (csf_mask[(size_t)bs * W + lane] != 0) ? 1 : 0;
    const unsigned long long bal = __ballot(pad);
    const int valid = W - (int)__popcll(bal);
    len = (valid == 0) ? NEG_BIG : (float)valid;
  }
  __syncthreads();

  if (t < 9) {
    const int b0 = blk >> 6, s0 = blk & 63;
    ws[WS_SC + ((size_t)t * B + b0) * S + s0] =
        (part[0][0][t] + part[0][1][t]) / len;
  }
  if (j1csf && t >= 64 && t < 73) {
    const int q = t - 64;
    const int b1 = g1 >> 6, s1 = g1 & 63;
    ws[WS_SC + ((size_t)q * B + b1) * S + s1] =
        (part[1][0][q] + part[1][1][q]) / len;
  }

  __threadfence();
  cg::this_grid().sync();

  // ---- phase C: per-wave gather + output writes ----
  for (int row = blk * 2 + wv; row < B * O * W; row += NBLK * 2) {
    const int w = row & 31;
    const int bo = row >> 5;
    const int b = bo >> 3;
    const int o = bo & 7;

    float vq_ = ws[WS_SC + (size_t)b * S + lane];
    int iq = lane;
    ARGMAX(vq_, iq);
    float vo_ = ws[WS_SC + ((size_t)(1 + o) * B + b) * S + lane];
    int io = lane;
    ARGMAX(vo_, io);

    const bool zero = (opt_sum[bo] != 0);
    f4 a0 = {0.f, 0.f, 0.f, 0.f}, a1 = a0, b0 = a0, b1 = a0;
    if (!zero) {
      const f4* qrow = (const f4*)csf + (((size_t)b * S + iq) * W + w) * 128;
      a0 = qrow[lane];
      a1 = qrow[64 + lane];
      const f4* orow = (const f4*)csf + ((size_t)io * W + w) * 128;
      b0 = orow[lane];
      b1 = orow[64 + lane];
    }
    f4* oq = (f4*)(out + (size_t)row * D);
    f4* oo = (f4*)(out + OFF_OPT + (size_t)row * D);
    __builtin_nontemporal_store(a0, oq + lane);
    __builtin_nontemporal_store(a1, oq + 64 + lane);
    __builtin_nontemporal_store(b0, oo + lane);
    __builtin_nontemporal_store(b1, oo + 64 + lane);

    float aq = fabsf(a0.x) + fabsf(a0.y) + fabsf(a0.z) + fabsf(a0.w) +
               fabsf(a1.x) + fabsf(a1.y) + fabsf(a1.z) + fabsf(a1.w);
    float ao = fabsf(b0.x) + fabsf(b0.y) + fabsf(b0.z) + fabsf(b0.w) +
               fabsf(b1.x) + fabsf(b1.y) + fabsf(b1.z) + fabsf(b1.w);
    RED(aq);
    RED(ao);
    if (lane == 0) {
      out[OFF_QMASK + row] = (aq == 0.f) ? 1.f : 0.f;
      out[OFF_OMASK + row] = (ao == 0.f) ? 1.f : 0.f;
    }
  }
}

// ---------------------------------------------------------------------------
// Legacy fallback path (only if cooperative launch unavailable).
// ---------------------------------------------------------------------------
template <int ROWS>
__device__ inline void rowsum4(const f4* __restrict__ src, f4* __restrict__ dst,
                               int t) {
  const int quarter = t >> 7;
  const int col = t & 127;
  const f4* p = src + (size_t)(quarter * (ROWS / 4)) * 128 + col;
  f4 acc = {0.f, 0.f, 0.f, 0.f};
  #pragma unroll
  for (int r = 0; r < ROWS / 4; ++r) acc += p[(size_t)r * 128];
  __shared__ f4 tmp[3][128];
  if (quarter) tmp[quarter - 1][col] = acc;
  __syncthreads();
  if (quarter == 0) dst[col] = acc + tmp[0][col] + tmp[1][col] + tmp[2][col];
}

__global__ __launch_bounds__(512) void k_qosum(
    const float* __restrict__ que, const float* __restrict__ opt,
    float* __restrict__ ws) {
  const int blk = blockIdx.x;
  const int t = threadIdx.x;
  if (blk < B) {
    rowsum4<LQ>((const f4*)que + (size_t)blk * LQ * 128,
                (f4*)(ws + WS_QSUMH) + (size_t)blk * 256, t);
    if (t < 128) {
      f4 z = {0.f, 0.f, 0.f, 0.f};
      ((f4*)(ws + WS_QSUMH))[(size_t)blk * 256 + 128 + t] = z;
    }
  } else {
    const int bo = blk - B;
    rowsum4<LO>((const f4*)opt + (size_t)bo * LO * 128,
                (f4*)(ws + WS_OSUM) + (size_t)bo * 128, t);
  }
}

__global__ __launch_bounds__(128) void k_score(
    const float* __restrict__ csf, const unsigned char* __restrict__ csf_mask,
    float* __restrict__ ws) {
  const int bs = blockIdx.x;
  const int b = bs >> 6;
  const int s = bs & 63;
  const int t = threadIdx.x;
  const int wv = t >> 6;
  const int lane = t & 63;

  const f4* p = (const f4*)csf + (size_t)bs * 4096 + t;
  f4 acc = {0.f, 0.f, 0.f, 0.f};
  #pragma unroll 8
  for (int r = 0; r < 32; ++r) acc += p[(size_t)r * 128];

  __shared__ float part[2][9];
  dots9(ws, acc, b, wv, lane, part);

  int pad = 0;
  if (lane < W) pad = (csf_mask[(size_t)bs * W + lane] != 0) ? 1 : 0;
  const unsigned long long bal = __ballot(pad);
  const int valid = W - (int)__popcll(bal);
  const float len = (valid == 0) ? NEG_BIG : (float)valid;

  __syncthreads();
  if (t < 9)
    ws[WS_SC + ((size_t)t * B + b) * S + s] = (part[0][t] + part[1][t]) / len;
}

__global__ __launch_bounds__(128) void k_gather(
    const float* __restrict__ csf, const unsigned char* __restrict__ opt_sum,
    const float* __restrict__ ws, float* __restrict__ out) {
  const int bow = blockIdx.x;
  const int w = bow & 31;
  const int bo = bow >> 5;
  const int b = bo >> 3;
  const int o = bo & 7;
  const int t = threadIdx.x;
  const int wv = t >> 6;
  const int lane = t & 63;

  __shared__ int sh_ix[2];
  {
    const int q = (wv == 0) ? 0 : (1 + o);
    float v = ws[WS_SC + ((size_t)q * B + b) * S + lane];
    int idx = lane;
    ARGMAX(v, idx);
    if (lane == 0) sh_ix[wv] = idx;
  }
  __syncthreads();

  const bool zero = (opt_sum[bo] != 0);
  f4 vq = {0.f, 0.f, 0.f, 0.f};
  f4 vo = {0.f, 0.f, 0.f, 0.f};
  if (!zero) {
    const int iq = sh_ix[0];
    const int io = sh_ix[1];
    vq = ((const f4*)csf)[(((size_t)b * S + iq) * W + w) * 128 + t];
    vo = ((const f4*)csf)[((size_t)io * W + w) * 128 + t];
  }
  __builtin_nontemporal_store(vq, (f4*)(out + (size_t)bow * D) + t);
  __builtin_nontemporal_store(vo, (f4*)(out + OFF_OPT + (size_t)bow * D) + t);

  float aq = fabsf(vq.x) + fabsf(vq.y) + fabsf(vq.z) + fabsf(vq.w);
  float ao = fabsf(vo.x) + fabsf(vo.y) + fabsf(vo.z) + fabsf(vo.w);
  RED(aq);
  RED(ao);

  __shared__ float sq[2], so[2];
  if (lane == 0) { sq[wv] = aq; so[wv] = ao; }
  __syncthreads();
  if (t == 0) {
    out[OFF_QMASK + bow] = ((sq[0] + sq[1]) == 0.f) ? 1.f : 0.f;
    out[OFF_OMASK + bow] = ((so[0] + so[1]) == 0.f) ? 1.f : 0.f;
  }
}

extern "C" void kernel_launch(void* const* d_in, const int* in_sizes, int n_in,
                              void* d_out, int out_size, void* d_ws, size_t ws_size,
                              hipStream_t stream) {
  const float* que = (const float*)d_in[0];
  const float* opt = (const float*)d_in[1];
  const float* csf = (const float*)d_in[2];
  const unsigned char* csf_mask = (const unsigned char*)d_in[3];
  const unsigned char* opt_sum = (const unsigned char*)d_in[4];
  float* out = (float*)d_out;
  float* ws = (float*)d_ws;

  // Cooperative path: requires all NBLK blocks co-resident.
  int coop = 0;
  {
    int dev = 0;
    hipDeviceProp_t prop{};
    int mb = 0;
    if (hipGetDevice(&dev) == hipSuccess &&
        hipGetDeviceProperties(&prop, dev) == hipSuccess &&
        hipOccupancyMaxActiveBlocksPerMultiprocessor(&mb, k_fused, 128, 0) ==
            hipSuccess) {
      if (prop.cooperativeLaunch &&
          (long)mb * prop.multiProcessorCount >= NBLK)
        coop = 1;
    }
  }

  if (coop) {
    void* args[] = {(void*)&que, (void*)&opt, (void*)&csf, (void*)&csf_mask,
                    (void*)&opt_sum, (void*)&ws, (void*)&out};
    if (hipLaunchCooperativeKernel(k_fused, dim3(NBLK), dim3(128), args, 0,
                                   stream) != hipSuccess)
      coop = 0;
  }
  if (!coop) {
    k_qosum<<<B + B * O, 512, 0, stream>>>(que, opt, ws);
    k_score<<<B * S, 128, 0, stream>>>(csf, csf_mask, ws);
    k_gather<<<B * O * W, 128, 0, stream>>>(csf, opt_sum, ws, out);
  }
}

// Round 7
// 70.386 us; speedup vs baseline: 2.0763x; 1.0028x over previous
//
#include <hip/hip_runtime.h>
#include <stddef.h>

// Problem dims (fixed by reference)
#define B  64
#define LQ 64
#define O  8
#define LO 32
#define S  64
#define W  32
#define D  512

#define NEG_BIG (-9.0e15f)

// Output layout (flat float, concatenated in return order)
#define QUE_CSF_SZ  (B*O*W*D)
#define MASK_SZ     (B*O*W)
#define OFF_QMASK   (QUE_CSF_SZ)
#define OFF_OPT     (QUE_CSF_SZ + MASK_SZ)
#define OFF_OMASK   (QUE_CSF_SZ + MASK_SZ + QUE_CSF_SZ)

// Workspace layout (floats)
#define WS_QSUMH 0                         // B*2*D   (qsum halves)
#define WS_OSUM  (B*2*D)                   // B*O*D
#define WS_SC    (B*2*D + B*O*D)           // 9*B*S scores [(q*B+b)*S+s]
#define WS_FLAGS (WS_SC + 9*B*S)           // ints: done_sum, next_chunk, done_score[64]
#define N_FLAGS  66

// Pipeline geometry
#define NBLK      2048      // 8 blocks/CU x 256 CU — co-resident
#define N_SUM     640       // 128 que-halves + 512 opt units (32 rows x 512 cols each)
#define N_CSF     4096      // csf chunks (b,s), 64KB each

using f4 = __attribute__((ext_vector_type(4))) float;

__device__ inline float dot4(f4 a, f4 b) {
  return a.x * b.x + a.y * b.y + a.z * b.z + a.w * b.w;
}

#define RED(v)                \
  do {                        \
    v += __shfl_xor(v, 32);   \
    v += __shfl_xor(v, 16);   \
    v += __shfl_xor(v, 8);    \
    v += __shfl_xor(v, 4);    \
    v += __shfl_xor(v, 2);    \
    v += __shfl_xor(v, 1);    \
  } while (0)

#define ARGMAX(v, idx)                                                \
  do {                                                                \
    for (int off_ = 32; off_; off_ >>= 1) {                           \
      float ov_ = __shfl_xor(v, off_);                                \
      int oi_ = __shfl_xor(idx, off_);                                \
      if (ov_ > v || (ov_ == v && oi_ < idx)) { v = ov_; idx = oi_; } \
    }                                                                 \
  } while (0)

// Sum 32 rows of one f4 column (col = t), row stride 128 f4 (= 512 floats).
__device__ inline f4 stream32(const f4* __restrict__ p, int t) {
  f4 acc = {0.f, 0.f, 0.f, 0.f};
  #pragma unroll 8
  for (int r = 0; r < 32; ++r) acc += p[(size_t)r * 128 + t];
  return acc;
}

// 9 dots of a csum fragment against qsum[b] (2 halves) + osum[b,0..7];
// per-wave reduce; lane0 deposits into part[wv][0..8].
__device__ inline void dots9(const float* __restrict__ ws, f4 acc, int b,
                             int wv, int lane, float part[2][9]) {
  const f4* qh = (const f4*)(ws + WS_QSUMH) + (size_t)b * 256;
  const int t = wv * 64 + lane;
  f4 qs = qh[t] + qh[128 + t];
  float pq = dot4(acc, qs);
  float po[O];
  #pragma unroll
  for (int o = 0; o < O; ++o)
    po[o] = dot4(acc, ((const f4*)(ws + WS_OSUM))[((size_t)(b * O + o)) * 128 + t]);
  RED(pq);
  #pragma unroll
  for (int o = 0; o < O; ++o) RED(po[o]);
  if (lane == 0) {
    part[wv][0] = pq;
    #pragma unroll
    for (int o = 0; o < O; ++o) part[wv][1 + o] = po[o];
  }
}

__device__ inline void spin_until(int* p, int target) {
  if (threadIdx.x == 0) {
    while (__hip_atomic_load(p, __ATOMIC_ACQUIRE, __HIP_MEMORY_SCOPE_AGENT) <
           target)
      __builtin_amdgcn_s_sleep(8);
  }
  __syncthreads();
  __threadfence();  // acquire for all waves' subsequent plain reads
}

// ---------------------------------------------------------------------------
// Persistent-block pipeline (single normal launch, NO grid-wide barrier):
//   stage 1 (blocks 0..639): one que/opt sum unit -> ws, bump done_sum
//   stage 2 (all blocks): csf chunks via atomic dispenser -> stream to regs,
//            spin once on done_sum, score, bump done_score[b]
//   stage 3 (all blocks): 8 output rows of one (b,o): spin done_score[b],
//            argmax, gather, nt-store outputs + masks
// Safe because all NBLK blocks are co-resident (8 blocks/CU, verified at
// launch) and no block spins before finishing its producer work.
// ---------------------------------------------------------------------------
__global__ __launch_bounds__(128, 4) void k_pipe(
    const float* __restrict__ que, const float* __restrict__ opt,
    const float* __restrict__ csf, const unsigned char* __restrict__ csf_mask,
    const unsigned char* __restrict__ opt_sum, float* __restrict__ ws,
    float* __restrict__ out) {
  const int blk = blockIdx.x;
  const int t = threadIdx.x;      // 0..127, owns f4 column t
  const int wv = t >> 6;
  const int lane = t & 63;

  int* flags = (int*)(ws + WS_FLAGS);
  int* done_sum = flags;          // target N_SUM
  int* next_chunk = flags + 1;    // csf chunk dispenser
  int* done_score = flags + 2;    // [B], target S

  // ---- stage 1: sum units (producers never spin before producing) ----
  if (blk < N_SUM) {
    f4 acc;
    if (blk < 128) {  // que half u: b=u>>1, h=u&1 -> contiguous chunk u
      acc = stream32((const f4*)que + (size_t)blk * 4096, t);
      ((f4*)(ws + WS_QSUMH))[(size_t)blk * 128 + t] = acc;
    } else {          // opt unit bo
      const int bo = blk - 128;
      acc = stream32((const f4*)opt + (size_t)bo * 4096, t);
      ((f4*)(ws + WS_OSUM))[(size_t)bo * 128 + t] = acc;
    }
    __syncthreads();  // drain block stores
    if (t == 0) {
      __threadfence();
      __hip_atomic_fetch_add(done_sum, 1, __ATOMIC_RELEASE,
                             __HIP_MEMORY_SCOPE_AGENT);
    }
  }

  // ---- stage 2: csf chunks via dispenser ----
  __shared__ int sh_c;
  __shared__ float part[2][9];
  bool waited = false;
  for (;;) {
    if (t == 0) sh_c = atomicAdd(next_chunk, 1);
    __syncthreads();
    const int c = sh_c;
    __syncthreads();
    if (c >= N_CSF) break;
    const int b = c >> 6, s = c & 63;

    f4 acc = stream32((const f4*)csf + (size_t)c * 4096, t);

    if (!waited) {  // sums are ~13% of traffic; usually already done
      spin_until(done_sum, N_SUM);
      waited = true;
    }

    dots9(ws, acc, b, wv, lane, part);

    int pad = 0;
    if (lane < W) pad = (csf_mask[(size_t)c * W + lane] != 0) ? 1 : 0;
    const unsigned long long bal = __ballot(pad);
    const int valid = W - (int)__popcll(bal);
    const float len = (valid == 0) ? NEG_BIG : (float)valid;

    __syncthreads();
    if (t < 9)
      ws[WS_SC + ((size_t)t * B + b) * S + s] = (part[0][t] + part[1][t]) / len;
    __syncthreads();  // drain score stores
    if (t == 0) {
      __threadfence();
      __hip_atomic_fetch_add(&done_score[b], 1, __ATOMIC_RELEASE,
                             __HIP_MEMORY_SCOPE_AGENT);
    }
  }

  // ---- stage 3: gather 8 rows of one (b,o) ----
  {
    const int b = blk >> 5;
    const int o = (blk >> 2) & 7;
    const int w0 = (blk & 3) * 8;

    spin_until(&done_score[b], S);

    // argmax (first-index tie-break = jnp.argmax); result in every lane
    float vq_ = ws[WS_SC + (size_t)b * S + lane];
    int iq = lane;
    ARGMAX(vq_, iq);
    float vo_ = ws[WS_SC + ((size_t)(1 + o) * B + b) * S + lane];
    int io = lane;
    ARGMAX(vo_, io);

    const bool zero = (opt_sum[b * O + o] != 0);
    const f4* qbase = (const f4*)csf + ((size_t)b * S + iq) * W * 128;
    const f4* obase = (const f4*)csf + (size_t)io * W * 128;  // csf[0][io]

    #pragma unroll
    for (int i = 0; i < 4; ++i) {
      const int w = w0 + wv * 4 + i;
      const int row = (b * O + o) * W + w;

      f4 a0 = {0.f, 0.f, 0.f, 0.f}, a1 = a0, b0 = a0, b1 = a0;
      if (!zero) {
        a0 = qbase[(size_t)w * 128 + lane];
        a1 = qbase[(size_t)w * 128 + 64 + lane];
        b0 = obase[(size_t)w * 128 + lane];
        b1 = obase[(size_t)w * 128 + 64 + lane];
      }
      f4* oq = (f4*)(out + (size_t)row * D);
      f4* oo = (f4*)(out + OFF_OPT + (size_t)row * D);
      __builtin_nontemporal_store(a0, oq + lane);
      __builtin_nontemporal_store(a1, oq + 64 + lane);
      __builtin_nontemporal_store(b0, oo + lane);
      __builtin_nontemporal_store(b1, oo + 64 + lane);

      float aq = fabsf(a0.x) + fabsf(a0.y) + fabsf(a0.z) + fabsf(a0.w) +
                 fabsf(a1.x) + fabsf(a1.y) + fabsf(a1.z) + fabsf(a1.w);
      float ao = fabsf(b0.x) + fabsf(b0.y) + fabsf(b0.z) + fabsf(b0.w) +
                 fabsf(b1.x) + fabsf(b1.y) + fabsf(b1.z) + fabsf(b1.w);
      RED(aq);
      RED(ao);
      if (lane == 0) {
        out[OFF_QMASK + row] = (aq == 0.f) ? 1.f : 0.f;
        out[OFF_OMASK + row] = (ao == 0.f) ? 1.f : 0.f;
      }
    }
  }
}

// ---------------------------------------------------------------------------
// Legacy fallback path (R4 structure) if co-residency can't be verified.
// ---------------------------------------------------------------------------
template <int ROWS>
__device__ inline void rowsum4(const f4* __restrict__ src, f4* __restrict__ dst,
                               int t) {
  const int quarter = t >> 7;
  const int col = t & 127;
  const f4* p = src + (size_t)(quarter * (ROWS / 4)) * 128 + col;
  f4 acc = {0.f, 0.f, 0.f, 0.f};
  #pragma unroll
  for (int r = 0; r < ROWS / 4; ++r) acc += p[(size_t)r * 128];
  __shared__ f4 tmp[3][128];
  if (quarter) tmp[quarter - 1][col] = acc;
  __syncthreads();
  if (quarter == 0) dst[col] = acc + tmp[0][col] + tmp[1][col] + tmp[2][col];
}

__global__ __launch_bounds__(512) void k_qosum(
    const float* __restrict__ que, const float* __restrict__ opt,
    float* __restrict__ ws) {
  const int blk = blockIdx.x;
  const int t = threadIdx.x;
  if (blk < B) {
    rowsum4<LQ>((const f4*)que + (size_t)blk * LQ * 128,
                (f4*)(ws + WS_QSUMH) + (size_t)blk * 256, t);
    if (t < 128) {
      f4 z = {0.f, 0.f, 0.f, 0.f};
      ((f4*)(ws + WS_QSUMH))[(size_t)blk * 256 + 128 + t] = z;
    }
  } else {
    const int bo = blk - B;
    rowsum4<LO>((const f4*)opt + (size_t)bo * LO * 128,
                (f4*)(ws + WS_OSUM) + (size_t)bo * 128, t);
  }
}

__global__ __launch_bounds__(128) void k_score(
    const float* __restrict__ csf, const unsigned char* __restrict__ csf_mask,
    float* __restrict__ ws) {
  const int bs = blockIdx.x;
  const int b = bs >> 6;
  const int s = bs & 63;
  const int t = threadIdx.x;
  const int wv = t >> 6;
  const int lane = t & 63;

  f4 acc = stream32((const f4*)csf + (size_t)bs * 4096, t);

  __shared__ float part[2][9];
  dots9(ws, acc, b, wv, lane, part);

  int pad = 0;
  if (lane < W) pad = (csf_mask[(size_t)bs * W + lane] != 0) ? 1 : 0;
  const unsigned long long bal = __ballot(pad);
  const int valid = W - (int)__popcll(bal);
  const float len = (valid == 0) ? NEG_BIG : (float)valid;

  __syncthreads();
  if (t < 9)
    ws[WS_SC + ((size_t)t * B + b) * S + s] = (part[0][t] + part[1][t]) / len;
}

__global__ __launch_bounds__(128) void k_gather(
    const float* __restrict__ csf, const unsigned char* __restrict__ opt_sum,
    const float* __restrict__ ws, float* __restrict__ out) {
  const int bow = blockIdx.x;
  const int w = bow & 31;
  const int bo = bow >> 5;
  const int b = bo >> 3;
  const int o = bo & 7;
  const int t = threadIdx.x;
  const int wv = t >> 6;
  const int lane = t & 63;

  __shared__ int sh_ix[2];
  {
    const int q = (wv == 0) ? 0 : (1 + o);
    float v = ws[WS_SC + ((size_t)q * B + b) * S + lane];
    int idx = lane;
    ARGMAX(v, idx);
    if (lane == 0) sh_ix[wv] = idx;
  }
  __syncthreads();

  const bool zero = (opt_sum[bo] != 0);
  f4 vq = {0.f, 0.f, 0.f, 0.f};
  f4 vo = {0.f, 0.f, 0.f, 0.f};
  if (!zero) {
    const int iq = sh_ix[0];
    const int io = sh_ix[1];
    vq = ((const f4*)csf)[(((size_t)b * S + iq) * W + w) * 128 + t];
    vo = ((const f4*)csf)[((size_t)io * W + w) * 128 + t];
  }
  __builtin_nontemporal_store(vq, (f4*)(out + (size_t)bow * D) + t);
  __builtin_nontemporal_store(vo, (f4*)(out + OFF_OPT + (size_t)bow * D) + t);

  float aq = fabsf(vq.x) + fabsf(vq.y) + fabsf(vq.z) + fabsf(vq.w);
  float ao = fabsf(vo.x) + fabsf(vo.y) + fabsf(vo.z) + fabsf(vo.w);
  RED(aq);
  RED(ao);

  __shared__ float sq[2], so[2];
  if (lane == 0) { sq[wv] = aq; so[wv] = ao; }
  __syncthreads();
  if (t == 0) {
    out[OFF_QMASK + bow] = ((sq[0] + sq[1]) == 0.f) ? 1.f : 0.f;
    out[OFF_OMASK + bow] = ((so[0] + so[1]) == 0.f) ? 1.f : 0.f;
  }
}

extern "C" void kernel_launch(void* const* d_in, const int* in_sizes, int n_in,
                              void* d_out, int out_size, void* d_ws, size_t ws_size,
                              hipStream_t stream) {
  const float* que = (const float*)d_in[0];
  const float* opt = (const float*)d_in[1];
  const float* csf = (const float*)d_in[2];
  const unsigned char* csf_mask = (const unsigned char*)d_in[3];
  const unsigned char* opt_sum = (const unsigned char*)d_in[4];
  float* out = (float*)d_out;
  float* ws = (float*)d_ws;

  // Verify co-residency: need 8 blocks/CU for the spin-waits to be safe.
  int ok = 0;
  {
    int mb = 0;
    if (hipOccupancyMaxActiveBlocksPerMultiprocessor(&mb, k_pipe, 128, 0) ==
            hipSuccess &&
        mb >= NBLK / 256)
      ok = 1;
  }

  if (ok) {
    hipMemsetAsync(ws + WS_FLAGS, 0, N_FLAGS * sizeof(int), stream);
    k_pipe<<<NBLK, 128, 0, stream>>>(que, opt, csf, csf_mask, opt_sum, ws, out);
  } else {
    k_qosum<<<B + B * O, 512, 0, stream>>>(que, opt, ws);
    k_score<<<B * S, 128, 0, stream>>>(csf, csf_mask, ws);
    k_gather<<<B * O * W, 128, 0, stream>>>(csf, opt_sum, ws, out);
  }
}